// Round 1
// baseline (1597.487 us; speedup 1.0000x reference)
//
#include <hip/hip_runtime.h>
#include <math.h>

#define D 256
#define WDECAY 1e-6f

// Kernel 1: new_i = rp_i * decay^i for i=1..3 (vectorized float4 streaming).
__global__ __launch_bounds__(256) void init_tables(
    const float* __restrict__ rp1, const float* __restrict__ rp2,
    const float* __restrict__ rp3, const float* __restrict__ times,
    const float* __restrict__ now_time, int E,
    float* __restrict__ new1, float* __restrict__ new2, float* __restrict__ new3,
    long long n4)
{
    float tlast = times[E - 1];
    float dec = expf(-WDECAY * (tlast - now_time[0]));
    float d2 = dec * dec;
    float d3 = d2 * dec;
    const float4* r1 = (const float4*)rp1;
    const float4* r2 = (const float4*)rp2;
    const float4* r3 = (const float4*)rp3;
    float4* n1 = (float4*)new1;
    float4* n2 = (float4*)new2;
    float4* n3 = (float4*)new3;
    long long i = (long long)blockIdx.x * blockDim.x + threadIdx.x;
    long long stride = (long long)gridDim.x * blockDim.x;
    for (; i < n4; i += stride) {
        float4 a = r1[i];
        a.x *= dec; a.y *= dec; a.z *= dec; a.w *= dec;
        n1[i] = a;
        float4 b = r2[i];
        b.x *= d2; b.y *= d2; b.z *= d2; b.w *= d2;
        n2[i] = b;
        float4 c = r3[i];
        c.x *= d3; c.y *= d3; c.z *= d3; c.w *= d3;
        n3[i] = c;
    }
}

// Kernel 2: one 256-thread block per edge; thread d handles column d.
// new_i[src] += rps[i-1][dst]*tw ; new_i[dst] += rps[i-1][src]*tw
// where rps[0]=rp0, rps[1]=rp1*dec, rps[2]=rp2*dec^2 (pre-update tables).
__global__ __launch_bounds__(256) void scatter_edges(
    const float* __restrict__ rp0, const float* __restrict__ rp1,
    const float* __restrict__ rp2, const float* __restrict__ times,
    const float* __restrict__ now_time,
    const int* __restrict__ src_ids, const int* __restrict__ dst_ids, int E,
    float* __restrict__ new1, float* __restrict__ new2, float* __restrict__ new3)
{
    int e = blockIdx.x;
    int d = threadIdx.x;
    float tlast = times[E - 1];
    float dec = expf(-WDECAY * (tlast - now_time[0]));
    float d2 = dec * dec;
    float tw = expf(-WDECAY * (tlast - times[e]));
    long long s = src_ids[e];
    long long t = dst_ids[e];
    long long so = s * D + d;
    long long to = t * D + d;

    float a0s = rp0[so], a0t = rp0[to];
    atomicAdd(&new1[so], a0t * tw);
    atomicAdd(&new1[to], a0s * tw);

    float a1s = rp1[so] * dec, a1t = rp1[to] * dec;
    atomicAdd(&new2[so], a1t * tw);
    atomicAdd(&new2[to], a1s * tw);

    float a2s = rp2[so] * d2, a2t = rp2[to] * d2;
    atomicAdd(&new3[so], a2t * tw);
    atomicAdd(&new3[to], a2s * tw);
}

// Kernel 3: one wave (64 threads) per query pair.
// Gather 8 rows -> LDS, Gram 8x8 -> log1p -> MLP 64->256->64 -> out.
__global__ __launch_bounds__(64) void pair_feature_mlp(
    const float* __restrict__ rp0, const float* __restrict__ new1,
    const float* __restrict__ new2, const float* __restrict__ new3,
    const int* __restrict__ q_src, const int* __restrict__ q_dst,
    const float* __restrict__ w1, const float* __restrict__ b1,
    const float* __restrict__ w2, const float* __restrict__ b2,
    float* __restrict__ out, int B)
{
    __shared__ float proj[8][260];   // stride 260: 260%32==4 -> conflict-free b128
    __shared__ float feat_s[64];
    __shared__ float h_s[256];

    int b = blockIdx.x;
    int lid = threadIdx.x;
    long long qs = q_src[b];
    long long qd = q_dst[b];

    const float* tabs[4] = {rp0, new1, new2, new3};
    // rows 0..3 = layers 0..3 at q_src ; rows 4..7 = layers 0..3 at q_dst
    #pragma unroll
    for (int r = 0; r < 4; ++r) {
        const float* tp = tabs[r];
        float4 v = *(const float4*)(tp + qs * D + lid * 4);
        *(float4*)&proj[r][lid * 4] = v;
        float4 w = *(const float4*)(tp + qd * D + lid * 4);
        *(float4*)&proj[r + 4][lid * 4] = w;
    }
    __syncthreads();

    // Gram: thread lid = p*8+q computes dot(proj[p], proj[q]) over 256 cols.
    int p = lid >> 3;
    int q = lid & 7;
    float acc = 0.f;
    #pragma unroll 8
    for (int k = 0; k < 64; ++k) {
        float4 a = *(const float4*)&proj[p][4 * k];
        float4 c = *(const float4*)&proj[q][4 * k];
        acc += a.x * c.x + a.y * c.y + a.z * c.z + a.w * c.w;
    }
    feat_s[lid] = log1pf(fmaxf(acc, 0.f));
    __syncthreads();

    // h = relu(feat @ w1 + b1): 256 hidden, 4 per thread.
    float h0 = b1[lid], h1 = b1[lid + 64], h2 = b1[lid + 128], h3 = b1[lid + 192];
    #pragma unroll 8
    for (int i = 0; i < 64; ++i) {
        float f = feat_s[i];
        const float* wr = w1 + i * 256;
        h0 += f * wr[lid];
        h1 += f * wr[lid + 64];
        h2 += f * wr[lid + 128];
        h3 += f * wr[lid + 192];
    }
    h_s[lid]       = fmaxf(h0, 0.f);
    h_s[lid + 64]  = fmaxf(h1, 0.f);
    h_s[lid + 128] = fmaxf(h2, 0.f);
    h_s[lid + 192] = fmaxf(h3, 0.f);
    __syncthreads();

    // out = h @ w2 + b2: 64 outputs, 1 per thread.
    float o = b2[lid];
    #pragma unroll 8
    for (int j = 0; j < 256; ++j) {
        o += h_s[j] * w2[j * 64 + lid];
    }
    out[(long long)b * 64 + lid] = o;
}

extern "C" void kernel_launch(void* const* d_in, const int* in_sizes, int n_in,
                              void* d_out, int out_size, void* d_ws, size_t ws_size,
                              hipStream_t stream)
{
    const float* rp0      = (const float*)d_in[0];
    const float* rp1      = (const float*)d_in[1];
    const float* rp2      = (const float*)d_in[2];
    const float* rp3      = (const float*)d_in[3];
    const float* times    = (const float*)d_in[4];
    const float* now_time = (const float*)d_in[5];
    const float* w1       = (const float*)d_in[6];
    const float* b1       = (const float*)d_in[7];
    const float* w2       = (const float*)d_in[8];
    const float* b2       = (const float*)d_in[9];
    const int*   src_ids  = (const int*)d_in[10];
    const int*   dst_ids  = (const int*)d_in[11];
    const int*   q_src    = (const int*)d_in[12];
    const int*   q_dst    = (const int*)d_in[13];
    float* out = (float*)d_out;

    long long ND = in_sizes[0];      // N * D
    int E = in_sizes[4];
    int B = in_sizes[12];

    float* new1 = (float*)d_ws;
    float* new2 = new1 + ND;
    float* new3 = new2 + ND;

    long long n4 = ND / 4;
    init_tables<<<2048, 256, 0, stream>>>(rp1, rp2, rp3, times, now_time, E,
                                          new1, new2, new3, n4);
    scatter_edges<<<E, 256, 0, stream>>>(rp0, rp1, rp2, times, now_time,
                                         src_ids, dst_ids, E, new1, new2, new3);
    pair_feature_mlp<<<B, 64, 0, stream>>>(rp0, new1, new2, new3, q_src, q_dst,
                                           w1, b1, w2, b2, out, B);
}

// Round 2
// 1056.935 us; speedup vs baseline: 1.5114x; 1.5114x over previous
//
#include <hip/hip_runtime.h>
#include <math.h>

#define D 256
#define WDECAY 1e-6f

// ---------------- CSR build ----------------

// Count incidences per node (both endpoints of every edge).
__global__ __launch_bounds__(256) void hist_kernel(
    const int* __restrict__ src, const int* __restrict__ dst, int E,
    int* __restrict__ cnt)
{
    int i = blockIdx.x * blockDim.x + threadIdx.x;
    if (i < 2 * E) {
        int n = (i < E) ? src[i] : dst[i - E];
        atomicAdd(&cnt[n], 1);
    }
}

// Single-block exclusive scan of cnt[0..N) -> row_start[0..N]; also
// overwrites cnt[i] with the start position (reused as the fill cursor).
#define SCAN_THREADS 1024
__global__ __launch_bounds__(SCAN_THREADS) void scan_kernel(
    int* __restrict__ cnt, int* __restrict__ row_start, int N)
{
    __shared__ int part[SCAN_THREADS];
    int tid = threadIdx.x;
    int per = (N + SCAN_THREADS - 1) / SCAN_THREADS;
    int lo = tid * per;
    int hi = lo + per; if (hi > N) hi = N;
    int s = 0;
    for (int i = lo; i < hi; ++i) s += cnt[i];
    part[tid] = s;
    __syncthreads();
    // Hillis-Steele inclusive scan
    for (int off = 1; off < SCAN_THREADS; off <<= 1) {
        int v = (tid >= off) ? part[tid - off] : 0;
        __syncthreads();
        part[tid] += v;
        __syncthreads();
    }
    int base = (tid == 0) ? 0 : part[tid - 1];
    for (int i = lo; i < hi; ++i) {
        int c = cnt[i];
        row_start[i] = base;
        cnt[i] = base;        // cursor
        base += c;
    }
    if (tid == SCAN_THREADS - 1) row_start[N] = base;
}

// Scatter (other, tw) into the per-node incidence lists.
__global__ __launch_bounds__(256) void fill_kernel(
    const int* __restrict__ src, const int* __restrict__ dst,
    const float* __restrict__ times, int E,
    int* __restrict__ cursor, int* __restrict__ adj_other,
    float* __restrict__ adj_tw)
{
    int i = blockIdx.x * blockDim.x + threadIdx.x;
    if (i >= 2 * E) return;
    int e = (i < E) ? i : i - E;
    int node  = (i < E) ? src[e] : dst[e];
    int other = (i < E) ? dst[e] : src[e];
    float tlast = times[E - 1];
    float w = expf(-WDECAY * (tlast - times[e]));
    int pos = atomicAdd(&cursor[node], 1);
    adj_other[pos] = other;
    adj_tw[pos] = w;
}

// One wave per node: new_i[n] = rp_i[n]*dec^i + sum_j rp_{i-1}[other_j]*dec^{i-1}*tw_j
// Thread lid covers columns [4*lid, 4*lid+4).
__global__ __launch_bounds__(64) void apply_updates(
    const float* __restrict__ rp0, const float* __restrict__ rp1,
    const float* __restrict__ rp2, const float* __restrict__ rp3,
    const float* __restrict__ times, const float* __restrict__ now_time, int E,
    const int* __restrict__ row_start, const int* __restrict__ adj_other,
    const float* __restrict__ adj_tw,
    float* __restrict__ new1, float* __restrict__ new2, float* __restrict__ new3)
{
    int n = blockIdx.x;
    int lid = threadIdx.x;
    float tlast = times[E - 1];
    float dec = expf(-WDECAY * (tlast - now_time[0]));
    float d2 = dec * dec;
    float d3 = d2 * dec;

    long long base = (long long)n * D + lid * 4;
    float4 i1 = *(const float4*)(rp1 + base);
    float4 i2 = *(const float4*)(rp2 + base);
    float4 i3 = *(const float4*)(rp3 + base);
    float4 acc1 = make_float4(i1.x * dec, i1.y * dec, i1.z * dec, i1.w * dec);
    float4 acc2 = make_float4(i2.x * d2, i2.y * d2, i2.z * d2, i2.w * d2);
    float4 acc3 = make_float4(i3.x * d3, i3.y * d3, i3.z * d3, i3.w * d3);

    int s = row_start[n];
    int e = row_start[n + 1];
    for (int j = s; j < e; ++j) {
        int o = adj_other[j];
        float w = adj_tw[j];
        long long ob = (long long)o * D + lid * 4;
        float4 v0 = *(const float4*)(rp0 + ob);
        float4 v1 = *(const float4*)(rp1 + ob);
        float4 v2 = *(const float4*)(rp2 + ob);
        float w1f = w;
        float w2f = dec * w;
        float w3f = d2 * w;
        acc1.x += v0.x * w1f; acc1.y += v0.y * w1f; acc1.z += v0.z * w1f; acc1.w += v0.w * w1f;
        acc2.x += v1.x * w2f; acc2.y += v1.y * w2f; acc2.z += v1.z * w2f; acc2.w += v1.w * w2f;
        acc3.x += v2.x * w3f; acc3.y += v2.y * w3f; acc3.z += v2.z * w3f; acc3.w += v2.w * w3f;
    }
    *(float4*)(new1 + base) = acc1;
    *(float4*)(new2 + base) = acc2;
    *(float4*)(new3 + base) = acc3;
}

// ---------------- fallback (atomic) path ----------------

__global__ __launch_bounds__(256) void init_tables(
    const float* __restrict__ rp1, const float* __restrict__ rp2,
    const float* __restrict__ rp3, const float* __restrict__ times,
    const float* __restrict__ now_time, int E,
    float* __restrict__ new1, float* __restrict__ new2, float* __restrict__ new3,
    long long n4)
{
    float tlast = times[E - 1];
    float dec = expf(-WDECAY * (tlast - now_time[0]));
    float d2 = dec * dec;
    float d3 = d2 * dec;
    const float4* r1 = (const float4*)rp1;
    const float4* r2 = (const float4*)rp2;
    const float4* r3 = (const float4*)rp3;
    float4* n1 = (float4*)new1;
    float4* n2 = (float4*)new2;
    float4* n3 = (float4*)new3;
    long long i = (long long)blockIdx.x * blockDim.x + threadIdx.x;
    long long stride = (long long)gridDim.x * blockDim.x;
    for (; i < n4; i += stride) {
        float4 a = r1[i]; a.x *= dec; a.y *= dec; a.z *= dec; a.w *= dec; n1[i] = a;
        float4 b = r2[i]; b.x *= d2; b.y *= d2; b.z *= d2; b.w *= d2; n2[i] = b;
        float4 c = r3[i]; c.x *= d3; c.y *= d3; c.z *= d3; c.w *= d3; n3[i] = c;
    }
}

__global__ __launch_bounds__(256) void scatter_edges(
    const float* __restrict__ rp0, const float* __restrict__ rp1,
    const float* __restrict__ rp2, const float* __restrict__ times,
    const float* __restrict__ now_time,
    const int* __restrict__ src_ids, const int* __restrict__ dst_ids, int E,
    float* __restrict__ new1, float* __restrict__ new2, float* __restrict__ new3)
{
    int e = blockIdx.x;
    int d = threadIdx.x;
    float tlast = times[E - 1];
    float dec = expf(-WDECAY * (tlast - now_time[0]));
    float d2 = dec * dec;
    float tw = expf(-WDECAY * (tlast - times[e]));
    long long s = src_ids[e];
    long long t = dst_ids[e];
    long long so = s * D + d;
    long long to = t * D + d;
    float a0s = rp0[so], a0t = rp0[to];
    atomicAdd(&new1[so], a0t * tw);
    atomicAdd(&new1[to], a0s * tw);
    float a1s = rp1[so] * dec, a1t = rp1[to] * dec;
    atomicAdd(&new2[so], a1t * tw);
    atomicAdd(&new2[to], a1s * tw);
    float a2s = rp2[so] * d2, a2t = rp2[to] * d2;
    atomicAdd(&new3[so], a2t * tw);
    atomicAdd(&new3[to], a2s * tw);
}

// ---------------- pair feature + MLP ----------------

__global__ __launch_bounds__(64) void pair_feature_mlp(
    const float* __restrict__ rp0, const float* __restrict__ new1,
    const float* __restrict__ new2, const float* __restrict__ new3,
    const int* __restrict__ q_src, const int* __restrict__ q_dst,
    const float* __restrict__ w1, const float* __restrict__ b1,
    const float* __restrict__ w2, const float* __restrict__ b2,
    float* __restrict__ out, int B)
{
    __shared__ float proj[8][260];
    __shared__ float feat_s[64];
    __shared__ float h_s[256];

    int b = blockIdx.x;
    int lid = threadIdx.x;
    long long qs = q_src[b];
    long long qd = q_dst[b];

    const float* tabs[4] = {rp0, new1, new2, new3};
    #pragma unroll
    for (int r = 0; r < 4; ++r) {
        const float* tp = tabs[r];
        float4 v = *(const float4*)(tp + qs * D + lid * 4);
        *(float4*)&proj[r][lid * 4] = v;
        float4 w = *(const float4*)(tp + qd * D + lid * 4);
        *(float4*)&proj[r + 4][lid * 4] = w;
    }
    __syncthreads();

    int p = lid >> 3;
    int q = lid & 7;
    float acc = 0.f;
    #pragma unroll 8
    for (int k = 0; k < 64; ++k) {
        float4 a = *(const float4*)&proj[p][4 * k];
        float4 c = *(const float4*)&proj[q][4 * k];
        acc += a.x * c.x + a.y * c.y + a.z * c.z + a.w * c.w;
    }
    feat_s[lid] = log1pf(fmaxf(acc, 0.f));
    __syncthreads();

    float h0 = b1[lid], h1 = b1[lid + 64], h2 = b1[lid + 128], h3 = b1[lid + 192];
    #pragma unroll 8
    for (int i = 0; i < 64; ++i) {
        float f = feat_s[i];
        const float* wr = w1 + i * 256;
        h0 += f * wr[lid];
        h1 += f * wr[lid + 64];
        h2 += f * wr[lid + 128];
        h3 += f * wr[lid + 192];
    }
    h_s[lid]       = fmaxf(h0, 0.f);
    h_s[lid + 64]  = fmaxf(h1, 0.f);
    h_s[lid + 128] = fmaxf(h2, 0.f);
    h_s[lid + 192] = fmaxf(h3, 0.f);
    __syncthreads();

    float o = b2[lid];
    #pragma unroll 8
    for (int j = 0; j < 256; ++j) {
        o += h_s[j] * w2[j * 64 + lid];
    }
    out[(long long)b * 64 + lid] = o;
}

extern "C" void kernel_launch(void* const* d_in, const int* in_sizes, int n_in,
                              void* d_out, int out_size, void* d_ws, size_t ws_size,
                              hipStream_t stream)
{
    const float* rp0      = (const float*)d_in[0];
    const float* rp1      = (const float*)d_in[1];
    const float* rp2      = (const float*)d_in[2];
    const float* rp3      = (const float*)d_in[3];
    const float* times    = (const float*)d_in[4];
    const float* now_time = (const float*)d_in[5];
    const float* w1       = (const float*)d_in[6];
    const float* b1       = (const float*)d_in[7];
    const float* w2       = (const float*)d_in[8];
    const float* b2       = (const float*)d_in[9];
    const int*   src_ids  = (const int*)d_in[10];
    const int*   dst_ids  = (const int*)d_in[11];
    const int*   q_src    = (const int*)d_in[12];
    const int*   q_dst    = (const int*)d_in[13];
    float* out = (float*)d_out;

    long long ND = in_sizes[0];      // N * D
    int N = (int)(ND / D);
    int E = in_sizes[4];
    int B = in_sizes[12];

    float* new1 = (float*)d_ws;
    float* new2 = new1 + ND;
    float* new3 = new2 + ND;

    // CSR arrays after the three tables.
    size_t base_bytes = (size_t)3 * ND * sizeof(float);
    size_t csr_bytes = (size_t)(N + (N + 1) + 2 * E) * sizeof(int)
                     + (size_t)(2 * E) * sizeof(float);

    if (ws_size >= base_bytes + csr_bytes) {
        int* cnt       = (int*)(new3 + ND);          // N (reused as cursor)
        int* row_start = cnt + N;                    // N+1
        int* adj_other = row_start + N + 1;          // 2E
        float* adj_tw  = (float*)(adj_other + 2 * E);// 2E

        hipMemsetAsync(cnt, 0, (size_t)N * sizeof(int), stream);
        int twoE = 2 * E;
        hist_kernel<<<(twoE + 255) / 256, 256, 0, stream>>>(src_ids, dst_ids, E, cnt);
        scan_kernel<<<1, SCAN_THREADS, 0, stream>>>(cnt, row_start, N);
        fill_kernel<<<(twoE + 255) / 256, 256, 0, stream>>>(src_ids, dst_ids, times, E,
                                                            cnt, adj_other, adj_tw);
        apply_updates<<<N, 64, 0, stream>>>(rp0, rp1, rp2, rp3, times, now_time, E,
                                            row_start, adj_other, adj_tw,
                                            new1, new2, new3);
    } else {
        long long n4 = ND / 4;
        init_tables<<<2048, 256, 0, stream>>>(rp1, rp2, rp3, times, now_time, E,
                                              new1, new2, new3, n4);
        scatter_edges<<<E, 256, 0, stream>>>(rp0, rp1, rp2, times, now_time,
                                             src_ids, dst_ids, E, new1, new2, new3);
    }

    pair_feature_mlp<<<B, 64, 0, stream>>>(rp0, new1, new2, new3, q_src, q_dst,
                                           w1, b1, w2, b2, out, B);
}

// Round 3
// 816.294 us; speedup vs baseline: 1.9570x; 1.2948x over previous
//
#include <hip/hip_runtime.h>
#include <math.h>

#define D 256
#define WDECAY 1e-6f
#define CHUNK 1024   // elements per scan block (256 threads x 4)

// ---------------- CSR build ----------------

__global__ __launch_bounds__(256) void hist_kernel(
    const int* __restrict__ src, const int* __restrict__ dst, int E,
    int* __restrict__ cnt)
{
    int i = blockIdx.x * blockDim.x + threadIdx.x;
    if (i < 2 * E) {
        int n = (i < E) ? src[i] : dst[i - E];
        atomicAdd(&cnt[n], 1);
    }
}

// Pass 1: per-block (1024-elem chunk) sums, coalesced.
__global__ __launch_bounds__(256) void scan_partial(
    const int* __restrict__ cnt, int N, int* __restrict__ bsum)
{
    __shared__ int sdata[256];
    int b = blockIdx.x, t = threadIdx.x;
    int base = b * CHUNK + 4 * t;
    int s = 0;
    if (base + 3 < N) {
        int4 v = *(const int4*)(cnt + base);
        s = v.x + v.y + v.z + v.w;
    } else {
        for (int k = 0; k < 4; ++k)
            if (base + k < N) s += cnt[base + k];
    }
    sdata[t] = s;
    __syncthreads();
    for (int off = 128; off > 0; off >>= 1) {
        if (t < off) sdata[t] += sdata[t + off];
        __syncthreads();
    }
    if (t == 0) bsum[b] = sdata[0];
}

// Pass 2: exclusive scan of NB block sums (NB ~ 98), single block; also total.
__global__ __launch_bounds__(256) void scan_blocksums(
    int* __restrict__ bsum, int NB, int* __restrict__ row_start, int N)
{
    __shared__ int part[256];
    int t = threadIdx.x;
    int per = (NB + 255) / 256;
    int lo = t * per, hi = lo + per;
    if (hi > NB) hi = NB;
    int s = 0;
    for (int i = lo; i < hi; ++i) s += bsum[i];
    part[t] = s;
    __syncthreads();
    for (int off = 1; off < 256; off <<= 1) {
        int v = (t >= off) ? part[t - off] : 0;
        __syncthreads();
        part[t] += v;
        __syncthreads();
    }
    int base = (t == 0) ? 0 : part[t - 1];
    for (int i = lo; i < hi; ++i) {
        int c = bsum[i];
        bsum[i] = base;
        base += c;
    }
    if (t == 255) row_start[N] = part[255];
}

// Pass 3: block-local exclusive scan + block offset; writes row_start and
// rewrites cnt in place as the fill cursor (per-thread read-before-write).
__global__ __launch_bounds__(256) void scan_apply(
    int* __restrict__ cnt, const int* __restrict__ bsum,
    int* __restrict__ row_start, int N)
{
    __shared__ int part[256];
    int b = blockIdx.x, t = threadIdx.x;
    int base = b * CHUNK + 4 * t;
    int4 v = make_int4(0, 0, 0, 0);
    if (base + 3 < N) {
        v = *(const int4*)(cnt + base);
    } else {
        if (base + 0 < N) v.x = cnt[base + 0];
        if (base + 1 < N) v.y = cnt[base + 1];
        if (base + 2 < N) v.z = cnt[base + 2];
    }
    part[t] = v.x + v.y + v.z + v.w;
    __syncthreads();
    for (int off = 1; off < 256; off <<= 1) {
        int pv = (t >= off) ? part[t - off] : 0;
        __syncthreads();
        part[t] += pv;
        __syncthreads();
    }
    int p = bsum[b] + ((t == 0) ? 0 : part[t - 1]);
    int p0 = p, p1 = p0 + v.x, p2 = p1 + v.y, p3 = p2 + v.z;
    if (base + 0 < N) { row_start[base + 0] = p0; cnt[base + 0] = p0; }
    if (base + 1 < N) { row_start[base + 1] = p1; cnt[base + 1] = p1; }
    if (base + 2 < N) { row_start[base + 2] = p2; cnt[base + 2] = p2; }
    if (base + 3 < N) { row_start[base + 3] = p3; cnt[base + 3] = p3; }
}

__global__ __launch_bounds__(256) void fill_kernel(
    const int* __restrict__ src, const int* __restrict__ dst,
    const float* __restrict__ times, int E,
    int* __restrict__ cursor, int* __restrict__ adj_other,
    float* __restrict__ adj_tw)
{
    int i = blockIdx.x * blockDim.x + threadIdx.x;
    if (i >= 2 * E) return;
    int e = (i < E) ? i : i - E;
    int node  = (i < E) ? src[e] : dst[e];
    int other = (i < E) ? dst[e] : src[e];
    float tlast = times[E - 1];
    float w = expf(-WDECAY * (tlast - times[e]));
    int pos = atomicAdd(&cursor[node], 1);
    adj_other[pos] = other;
    adj_tw[pos] = w;
}

// One wave per (node, layer): new_{l+1}[n] = rp_{l+1}[n]*dec^{l+1}
//                                          + sum_j rp_l[other_j]*dec^l*tw_j
__global__ __launch_bounds__(64) void apply_updates(
    const float* __restrict__ rp0, const float* __restrict__ rp1,
    const float* __restrict__ rp2, const float* __restrict__ rp3,
    const float* __restrict__ times, const float* __restrict__ now_time, int E,
    const int* __restrict__ row_start, const int* __restrict__ adj_other,
    const float* __restrict__ adj_tw,
    float* __restrict__ new1, float* __restrict__ new2, float* __restrict__ new3)
{
    int n = blockIdx.x;
    int l = blockIdx.y;          // 0,1,2 -> builds new1,new2,new3
    int lid = threadIdx.x;
    float tlast = times[E - 1];
    float dec = expf(-WDECAY * (tlast - now_time[0]));

    const float* own; const float* gat; float* outp; float os, gs;
    if (l == 0)      { own = rp1; gat = rp0; outp = new1; os = dec;           gs = 1.f;       }
    else if (l == 1) { own = rp2; gat = rp1; outp = new2; os = dec * dec;     gs = dec;       }
    else             { own = rp3; gat = rp2; outp = new3; os = dec * dec * dec; gs = dec * dec; }

    long long base = (long long)n * D + lid * 4;
    float4 acc = *(const float4*)(own + base);
    acc.x *= os; acc.y *= os; acc.z *= os; acc.w *= os;

    int s = row_start[n];
    int e = row_start[n + 1];
    for (int j = s; j < e; ++j) {
        int o = adj_other[j];
        float w = adj_tw[j] * gs;
        float4 v = *(const float4*)(gat + (long long)o * D + lid * 4);
        acc.x += v.x * w; acc.y += v.y * w; acc.z += v.z * w; acc.w += v.w * w;
    }
    *(float4*)(outp + base) = acc;
}

// ---------------- fallback (atomic) path ----------------

__global__ __launch_bounds__(256) void init_tables(
    const float* __restrict__ rp1, const float* __restrict__ rp2,
    const float* __restrict__ rp3, const float* __restrict__ times,
    const float* __restrict__ now_time, int E,
    float* __restrict__ new1, float* __restrict__ new2, float* __restrict__ new3,
    long long n4)
{
    float tlast = times[E - 1];
    float dec = expf(-WDECAY * (tlast - now_time[0]));
    float d2 = dec * dec;
    float d3 = d2 * dec;
    const float4* r1 = (const float4*)rp1;
    const float4* r2 = (const float4*)rp2;
    const float4* r3 = (const float4*)rp3;
    float4* n1 = (float4*)new1;
    float4* n2 = (float4*)new2;
    float4* n3 = (float4*)new3;
    long long i = (long long)blockIdx.x * blockDim.x + threadIdx.x;
    long long stride = (long long)gridDim.x * blockDim.x;
    for (; i < n4; i += stride) {
        float4 a = r1[i]; a.x *= dec; a.y *= dec; a.z *= dec; a.w *= dec; n1[i] = a;
        float4 b = r2[i]; b.x *= d2; b.y *= d2; b.z *= d2; b.w *= d2; n2[i] = b;
        float4 c = r3[i]; c.x *= d3; c.y *= d3; c.z *= d3; c.w *= d3; n3[i] = c;
    }
}

__global__ __launch_bounds__(256) void scatter_edges(
    const float* __restrict__ rp0, const float* __restrict__ rp1,
    const float* __restrict__ rp2, const float* __restrict__ times,
    const float* __restrict__ now_time,
    const int* __restrict__ src_ids, const int* __restrict__ dst_ids, int E,
    float* __restrict__ new1, float* __restrict__ new2, float* __restrict__ new3)
{
    int e = blockIdx.x;
    int d = threadIdx.x;
    float tlast = times[E - 1];
    float dec = expf(-WDECAY * (tlast - now_time[0]));
    float d2 = dec * dec;
    float tw = expf(-WDECAY * (tlast - times[e]));
    long long s = src_ids[e];
    long long t = dst_ids[e];
    long long so = s * D + d;
    long long to = t * D + d;
    float a0s = rp0[so], a0t = rp0[to];
    atomicAdd(&new1[so], a0t * tw);
    atomicAdd(&new1[to], a0s * tw);
    float a1s = rp1[so] * dec, a1t = rp1[to] * dec;
    atomicAdd(&new2[so], a1t * tw);
    atomicAdd(&new2[to], a1s * tw);
    float a2s = rp2[so] * d2, a2t = rp2[to] * d2;
    atomicAdd(&new3[so], a2t * tw);
    atomicAdd(&new3[to], a2s * tw);
}

// ---------------- pair feature + MLP ----------------

__global__ __launch_bounds__(64) void pair_feature_mlp(
    const float* __restrict__ rp0, const float* __restrict__ new1,
    const float* __restrict__ new2, const float* __restrict__ new3,
    const int* __restrict__ q_src, const int* __restrict__ q_dst,
    const float* __restrict__ w1, const float* __restrict__ b1,
    const float* __restrict__ w2, const float* __restrict__ b2,
    float* __restrict__ out, int B)
{
    __shared__ float proj[8][260];   // stride 260 -> conflict-free b128
    __shared__ float feat_s[64];
    __shared__ float h_s[256];

    int b = blockIdx.x;
    int lid = threadIdx.x;
    long long qs = q_src[b];
    long long qd = q_dst[b];

    const float* tabs[4] = {rp0, new1, new2, new3};
    #pragma unroll
    for (int r = 0; r < 4; ++r) {
        const float* tp = tabs[r];
        float4 v = *(const float4*)(tp + qs * D + lid * 4);
        *(float4*)&proj[r][lid * 4] = v;
        float4 w = *(const float4*)(tp + qd * D + lid * 4);
        *(float4*)&proj[r + 4][lid * 4] = w;
    }
    __syncthreads();

    // Gram: thread lid = p*8+q
    int p = lid >> 3;
    int q = lid & 7;
    float acc = 0.f;
    #pragma unroll 8
    for (int k = 0; k < 64; ++k) {
        float4 a = *(const float4*)&proj[p][4 * k];
        float4 c = *(const float4*)&proj[q][4 * k];
        acc += a.x * c.x + a.y * c.y + a.z * c.z + a.w * c.w;
    }
    feat_s[lid] = log1pf(fmaxf(acc, 0.f));
    __syncthreads();

    // h = relu(feat @ w1 + b1): thread owns 4 CONSECUTIVE hidden units ->
    // one coalesced float4 w1 load per i.
    float4 hv = *(const float4*)(b1 + 4 * lid);
    #pragma unroll 4
    for (int i = 0; i < 64; ++i) {
        float f = feat_s[i];
        float4 w = *(const float4*)(w1 + i * 256 + 4 * lid);
        hv.x += f * w.x; hv.y += f * w.y; hv.z += f * w.z; hv.w += f * w.w;
    }
    *(float4*)&h_s[4 * lid] = make_float4(fmaxf(hv.x, 0.f), fmaxf(hv.y, 0.f),
                                          fmaxf(hv.z, 0.f), fmaxf(hv.w, 0.f));
    __syncthreads();

    // out = h @ w2 + b2: 4 independent partials for ILP; w2 loads coalesced.
    float o0 = 0.f, o1 = 0.f, o2 = 0.f, o3 = 0.f;
    #pragma unroll 4
    for (int j = 0; j < 256; j += 4) {
        o0 += h_s[j + 0] * w2[(j + 0) * 64 + lid];
        o1 += h_s[j + 1] * w2[(j + 1) * 64 + lid];
        o2 += h_s[j + 2] * w2[(j + 2) * 64 + lid];
        o3 += h_s[j + 3] * w2[(j + 3) * 64 + lid];
    }
    out[(long long)b * 64 + lid] = b2[lid] + (o0 + o1) + (o2 + o3);
}

extern "C" void kernel_launch(void* const* d_in, const int* in_sizes, int n_in,
                              void* d_out, int out_size, void* d_ws, size_t ws_size,
                              hipStream_t stream)
{
    const float* rp0      = (const float*)d_in[0];
    const float* rp1      = (const float*)d_in[1];
    const float* rp2      = (const float*)d_in[2];
    const float* rp3      = (const float*)d_in[3];
    const float* times    = (const float*)d_in[4];
    const float* now_time = (const float*)d_in[5];
    const float* w1       = (const float*)d_in[6];
    const float* b1       = (const float*)d_in[7];
    const float* w2       = (const float*)d_in[8];
    const float* b2       = (const float*)d_in[9];
    const int*   src_ids  = (const int*)d_in[10];
    const int*   dst_ids  = (const int*)d_in[11];
    const int*   q_src    = (const int*)d_in[12];
    const int*   q_dst    = (const int*)d_in[13];
    float* out = (float*)d_out;

    long long ND = in_sizes[0];      // N * D
    int N = (int)(ND / D);
    int E = in_sizes[4];
    int B = in_sizes[12];
    int NB = (N + CHUNK - 1) / CHUNK;

    float* new1 = (float*)d_ws;
    float* new2 = new1 + ND;
    float* new3 = new2 + ND;

    size_t base_bytes = (size_t)3 * ND * sizeof(float);
    size_t csr_bytes = (size_t)(N + (N + 1) + 2 * E + NB) * sizeof(int)
                     + (size_t)(2 * E) * sizeof(float);

    if (ws_size >= base_bytes + csr_bytes && NB <= 65536) {
        int* cnt       = (int*)(new3 + ND);           // N (becomes cursor)
        int* row_start = cnt + N;                     // N+1
        int* adj_other = row_start + N + 1;           // 2E
        float* adj_tw  = (float*)(adj_other + 2 * E); // 2E
        int* bsum      = (int*)(adj_tw + 2 * E);      // NB

        hipMemsetAsync(cnt, 0, (size_t)N * sizeof(int), stream);
        int twoE = 2 * E;
        hist_kernel<<<(twoE + 255) / 256, 256, 0, stream>>>(src_ids, dst_ids, E, cnt);
        scan_partial<<<NB, 256, 0, stream>>>(cnt, N, bsum);
        scan_blocksums<<<1, 256, 0, stream>>>(bsum, NB, row_start, N);
        scan_apply<<<NB, 256, 0, stream>>>(cnt, bsum, row_start, N);
        fill_kernel<<<(twoE + 255) / 256, 256, 0, stream>>>(src_ids, dst_ids, times, E,
                                                            cnt, adj_other, adj_tw);
        dim3 grid(N, 3);
        apply_updates<<<grid, 64, 0, stream>>>(rp0, rp1, rp2, rp3, times, now_time, E,
                                               row_start, adj_other, adj_tw,
                                               new1, new2, new3);
    } else {
        long long n4 = ND / 4;
        init_tables<<<2048, 256, 0, stream>>>(rp1, rp2, rp3, times, now_time, E,
                                              new1, new2, new3, n4);
        scatter_edges<<<E, 256, 0, stream>>>(rp0, rp1, rp2, times, now_time,
                                             src_ids, dst_ids, E, new1, new2, new3);
    }

    pair_feature_mlp<<<B, 64, 0, stream>>>(rp0, new1, new2, new3, q_src, q_dst,
                                           w1, b1, w2, b2, out, B);
}

// Round 4
// 783.443 us; speedup vs baseline: 2.0391x; 1.0419x over previous
//
#include <hip/hip_runtime.h>
#include <math.h>

#define D 256
#define WDECAY 1e-6f
#define CHUNK 1024   // elements per scan block (256 threads x 4)

// ---------------- CSR build ----------------

__global__ __launch_bounds__(256) void hist_kernel(
    const int* __restrict__ src, const int* __restrict__ dst, int E,
    int* __restrict__ cnt)
{
    int i = blockIdx.x * blockDim.x + threadIdx.x;
    if (i < 2 * E) {
        int n = (i < E) ? src[i] : dst[i - E];
        atomicAdd(&cnt[n], 1);
    }
}

__global__ __launch_bounds__(256) void scan_partial(
    const int* __restrict__ cnt, int N, int* __restrict__ bsum)
{
    __shared__ int sdata[256];
    int b = blockIdx.x, t = threadIdx.x;
    int base = b * CHUNK + 4 * t;
    int s = 0;
    if (base + 3 < N) {
        int4 v = *(const int4*)(cnt + base);
        s = v.x + v.y + v.z + v.w;
    } else {
        for (int k = 0; k < 4; ++k)
            if (base + k < N) s += cnt[base + k];
    }
    sdata[t] = s;
    __syncthreads();
    for (int off = 128; off > 0; off >>= 1) {
        if (t < off) sdata[t] += sdata[t + off];
        __syncthreads();
    }
    if (t == 0) bsum[b] = sdata[0];
}

__global__ __launch_bounds__(256) void scan_blocksums(
    int* __restrict__ bsum, int NB, int* __restrict__ row_start, int N)
{
    __shared__ int part[256];
    int t = threadIdx.x;
    int per = (NB + 255) / 256;
    int lo = t * per, hi = lo + per;
    if (hi > NB) hi = NB;
    int s = 0;
    for (int i = lo; i < hi; ++i) s += bsum[i];
    part[t] = s;
    __syncthreads();
    for (int off = 1; off < 256; off <<= 1) {
        int v = (t >= off) ? part[t - off] : 0;
        __syncthreads();
        part[t] += v;
        __syncthreads();
    }
    int base = (t == 0) ? 0 : part[t - 1];
    for (int i = lo; i < hi; ++i) {
        int c = bsum[i];
        bsum[i] = base;
        base += c;
    }
    if (t == 255) row_start[N] = part[255];
}

__global__ __launch_bounds__(256) void scan_apply(
    int* __restrict__ cnt, const int* __restrict__ bsum,
    int* __restrict__ row_start, int N)
{
    __shared__ int part[256];
    int b = blockIdx.x, t = threadIdx.x;
    int base = b * CHUNK + 4 * t;
    int4 v = make_int4(0, 0, 0, 0);
    if (base + 3 < N) {
        v = *(const int4*)(cnt + base);
    } else {
        if (base + 0 < N) v.x = cnt[base + 0];
        if (base + 1 < N) v.y = cnt[base + 1];
        if (base + 2 < N) v.z = cnt[base + 2];
    }
    part[t] = v.x + v.y + v.z + v.w;
    __syncthreads();
    for (int off = 1; off < 256; off <<= 1) {
        int pv = (t >= off) ? part[t - off] : 0;
        __syncthreads();
        part[t] += pv;
        __syncthreads();
    }
    int p = bsum[b] + ((t == 0) ? 0 : part[t - 1]);
    int p0 = p, p1 = p0 + v.x, p2 = p1 + v.y, p3 = p2 + v.z;
    if (base + 0 < N) { row_start[base + 0] = p0; cnt[base + 0] = p0; }
    if (base + 1 < N) { row_start[base + 1] = p1; cnt[base + 1] = p1; }
    if (base + 2 < N) { row_start[base + 2] = p2; cnt[base + 2] = p2; }
    if (base + 3 < N) { row_start[base + 3] = p3; cnt[base + 3] = p3; }
}

__global__ __launch_bounds__(256) void fill_kernel(
    const int* __restrict__ src, const int* __restrict__ dst,
    const float* __restrict__ times, int E,
    int* __restrict__ cursor, int* __restrict__ adj_other,
    float* __restrict__ adj_tw)
{
    int i = blockIdx.x * blockDim.x + threadIdx.x;
    if (i >= 2 * E) return;
    int e = (i < E) ? i : i - E;
    int node  = (i < E) ? src[e] : dst[e];
    int other = (i < E) ? dst[e] : src[e];
    float tlast = times[E - 1];
    float w = expf(-WDECAY * (tlast - times[e]));
    int pos = atomicAdd(&cursor[node], 1);
    adj_other[pos] = other;
    adj_tw[pos] = w;
}

// Mark nodes that appear in any query pair.
__global__ __launch_bounds__(256) void set_flags(
    const int* __restrict__ qs, const int* __restrict__ qd, int B,
    int* __restrict__ flag)
{
    int i = blockIdx.x * blockDim.x + threadIdx.x;
    if (i < B) {
        flag[qs[i]] = 1;
        flag[qd[i]] = 1;
    }
}

// Transpose w1 [64][256] -> w1t [256][64] so MLP weight rows are contiguous.
__global__ __launch_bounds__(256) void transpose_w1(
    const float* __restrict__ w1, float* __restrict__ w1t)
{
    int t = blockIdx.x * blockDim.x + threadIdx.x;   // t = o*64 + i
    if (t < 64 * 256) {
        int i = t & 63;
        int o = t >> 6;
        w1t[t] = w1[i * 256 + o];
    }
}

// One wave per (node, layer), ONLY for nodes read by the query phase.
__global__ __launch_bounds__(64) void apply_updates(
    const float* __restrict__ rp0, const float* __restrict__ rp1,
    const float* __restrict__ rp2, const float* __restrict__ rp3,
    const float* __restrict__ times, const float* __restrict__ now_time, int E,
    const int* __restrict__ row_start, const int* __restrict__ adj_other,
    const float* __restrict__ adj_tw, const int* __restrict__ flag,
    float* __restrict__ new1, float* __restrict__ new2, float* __restrict__ new3)
{
    int n = blockIdx.x;
    if (!flag[n]) return;          // row never read downstream
    int l = blockIdx.y;
    int lid = threadIdx.x;
    float tlast = times[E - 1];
    float dec = expf(-WDECAY * (tlast - now_time[0]));

    const float* own; const float* gat; float* outp; float os, gs;
    if (l == 0)      { own = rp1; gat = rp0; outp = new1; os = dec;             gs = 1.f;       }
    else if (l == 1) { own = rp2; gat = rp1; outp = new2; os = dec * dec;       gs = dec;       }
    else             { own = rp3; gat = rp2; outp = new3; os = dec * dec * dec; gs = dec * dec; }

    long long base = (long long)n * D + lid * 4;
    float4 acc = *(const float4*)(own + base);
    acc.x *= os; acc.y *= os; acc.z *= os; acc.w *= os;

    int s = row_start[n];
    int e = row_start[n + 1];
    for (int j = s; j < e; ++j) {
        int o = adj_other[j];
        float w = adj_tw[j] * gs;
        float4 v = *(const float4*)(gat + (long long)o * D + lid * 4);
        acc.x += v.x * w; acc.y += v.y * w; acc.z += v.z * w; acc.w += v.w * w;
    }
    *(float4*)(outp + base) = acc;
}

// ---------------- pair feature ----------------

// One wave per pair: gather 8 rows, 8x8 Gram over D=256, log1p -> feat[B,64].
__global__ __launch_bounds__(64) void gather_gram(
    const float* __restrict__ rp0, const float* __restrict__ new1,
    const float* __restrict__ new2, const float* __restrict__ new3,
    const int* __restrict__ q_src, const int* __restrict__ q_dst,
    float* __restrict__ feat, int B)
{
    __shared__ float proj[8][260];   // stride 260 -> conflict-free b128
    int b = blockIdx.x;
    int lid = threadIdx.x;
    long long qs = q_src[b];
    long long qd = q_dst[b];

    const float* tabs[4] = {rp0, new1, new2, new3};
    #pragma unroll
    for (int r = 0; r < 4; ++r) {
        const float* tp = tabs[r];
        float4 v = *(const float4*)(tp + qs * D + lid * 4);
        *(float4*)&proj[r][lid * 4] = v;
        float4 w = *(const float4*)(tp + qd * D + lid * 4);
        *(float4*)&proj[r + 4][lid * 4] = w;
    }
    __syncthreads();

    int p = lid >> 3;
    int q = lid & 7;
    float acc = 0.f;
    #pragma unroll 8
    for (int k = 0; k < 64; ++k) {
        float4 a = *(const float4*)&proj[p][4 * k];
        float4 c = *(const float4*)&proj[q][4 * k];
        acc += a.x * c.x + a.y * c.y + a.z * c.z + a.w * c.w;
    }
    feat[(long long)b * 64 + lid] = log1pf(fmaxf(acc, 0.f));
}

// ---------------- MLP: thread = pair, weights via wave-uniform scalar loads ----

__global__ __launch_bounds__(64) void mlp_kernel(
    const float* __restrict__ feat,
    const float* __restrict__ w1t,   // [256][64] transposed
    const float* __restrict__ b1,
    const float* __restrict__ w2,    // [256][64]
    const float* __restrict__ b2,
    float* __restrict__ out, int B)
{
    __shared__ float fs[64][68];     // 68: 16B-aligned rows, mild (free-ish) conflicts
    int t = threadIdx.x;
    int p0 = blockIdx.x * 64;

    // coalesced tile load: iteration r loads feat row (p0+r), lane t -> col t
    for (int r = 0; r < 64; ++r) {
        int pi = p0 + r;
        fs[r][t] = (pi < B) ? feat[(long long)pi * 64 + t] : 0.f;
    }
    __syncthreads();

    // my pair's 64 features into registers (row t of the tile)
    float f[64];
    #pragma unroll
    for (int i = 0; i < 64; i += 4) {
        float4 v = *(const float4*)&fs[t][i];
        f[i] = v.x; f[i + 1] = v.y; f[i + 2] = v.z; f[i + 3] = v.w;
    }

    float oacc[64];
    #pragma unroll
    for (int ou = 0; ou < 64; ++ou) oacc[ou] = 0.f;

    // hidden units one at a time; w1t/w2 rows are wave-uniform contiguous ->
    // scalar loads; h is per-thread.
    for (int o = 0; o < 256; ++o) {
        const float* w1r = w1t + o * 64;
        float h = b1[o];
        #pragma unroll
        for (int i = 0; i < 64; ++i) h += f[i] * w1r[i];
        h = fmaxf(h, 0.f);
        const float* w2r = w2 + o * 64;
        #pragma unroll
        for (int ou = 0; ou < 64; ++ou) oacc[ou] += h * w2r[ou];
    }

    int pi = p0 + t;
    if (pi < B) {
        float* op = out + (long long)pi * 64;
        #pragma unroll
        for (int ou = 0; ou < 64; ou += 4) {
            float4 v = make_float4(oacc[ou] + b2[ou], oacc[ou + 1] + b2[ou + 1],
                                   oacc[ou + 2] + b2[ou + 2], oacc[ou + 3] + b2[ou + 3]);
            *(float4*)(op + ou) = v;
        }
    }
}

// ---------------- fallback (atomic) path ----------------

__global__ __launch_bounds__(256) void init_tables(
    const float* __restrict__ rp1, const float* __restrict__ rp2,
    const float* __restrict__ rp3, const float* __restrict__ times,
    const float* __restrict__ now_time, int E,
    float* __restrict__ new1, float* __restrict__ new2, float* __restrict__ new3,
    long long n4)
{
    float tlast = times[E - 1];
    float dec = expf(-WDECAY * (tlast - now_time[0]));
    float d2 = dec * dec;
    float d3 = d2 * dec;
    const float4* r1 = (const float4*)rp1;
    const float4* r2 = (const float4*)rp2;
    const float4* r3 = (const float4*)rp3;
    float4* n1 = (float4*)new1;
    float4* n2 = (float4*)new2;
    float4* n3 = (float4*)new3;
    long long i = (long long)blockIdx.x * blockDim.x + threadIdx.x;
    long long stride = (long long)gridDim.x * blockDim.x;
    for (; i < n4; i += stride) {
        float4 a = r1[i]; a.x *= dec; a.y *= dec; a.z *= dec; a.w *= dec; n1[i] = a;
        float4 b = r2[i]; b.x *= d2; b.y *= d2; b.z *= d2; b.w *= d2; n2[i] = b;
        float4 c = r3[i]; c.x *= d3; c.y *= d3; c.z *= d3; c.w *= d3; n3[i] = c;
    }
}

__global__ __launch_bounds__(256) void scatter_edges(
    const float* __restrict__ rp0, const float* __restrict__ rp1,
    const float* __restrict__ rp2, const float* __restrict__ times,
    const float* __restrict__ now_time,
    const int* __restrict__ src_ids, const int* __restrict__ dst_ids, int E,
    float* __restrict__ new1, float* __restrict__ new2, float* __restrict__ new3)
{
    int e = blockIdx.x;
    int d = threadIdx.x;
    float tlast = times[E - 1];
    float dec = expf(-WDECAY * (tlast - now_time[0]));
    float d2 = dec * dec;
    float tw = expf(-WDECAY * (tlast - times[e]));
    long long s = src_ids[e];
    long long t = dst_ids[e];
    long long so = s * D + d;
    long long to = t * D + d;
    float a0s = rp0[so], a0t = rp0[to];
    atomicAdd(&new1[so], a0t * tw);
    atomicAdd(&new1[to], a0s * tw);
    float a1s = rp1[so] * dec, a1t = rp1[to] * dec;
    atomicAdd(&new2[so], a1t * tw);
    atomicAdd(&new2[to], a1s * tw);
    float a2s = rp2[so] * d2, a2t = rp2[to] * d2;
    atomicAdd(&new3[so], a2t * tw);
    atomicAdd(&new3[to], a2s * tw);
}

__global__ __launch_bounds__(64) void pair_feature_mlp(
    const float* __restrict__ rp0, const float* __restrict__ new1,
    const float* __restrict__ new2, const float* __restrict__ new3,
    const int* __restrict__ q_src, const int* __restrict__ q_dst,
    const float* __restrict__ w1, const float* __restrict__ b1,
    const float* __restrict__ w2, const float* __restrict__ b2,
    float* __restrict__ out, int B)
{
    __shared__ float proj[8][260];
    __shared__ float feat_s[64];
    __shared__ float h_s[256];

    int b = blockIdx.x;
    int lid = threadIdx.x;
    long long qs = q_src[b];
    long long qd = q_dst[b];

    const float* tabs[4] = {rp0, new1, new2, new3};
    #pragma unroll
    for (int r = 0; r < 4; ++r) {
        const float* tp = tabs[r];
        float4 v = *(const float4*)(tp + qs * D + lid * 4);
        *(float4*)&proj[r][lid * 4] = v;
        float4 w = *(const float4*)(tp + qd * D + lid * 4);
        *(float4*)&proj[r + 4][lid * 4] = w;
    }
    __syncthreads();

    int p = lid >> 3;
    int q = lid & 7;
    float acc = 0.f;
    #pragma unroll 8
    for (int k = 0; k < 64; ++k) {
        float4 a = *(const float4*)&proj[p][4 * k];
        float4 c = *(const float4*)&proj[q][4 * k];
        acc += a.x * c.x + a.y * c.y + a.z * c.z + a.w * c.w;
    }
    feat_s[lid] = log1pf(fmaxf(acc, 0.f));
    __syncthreads();

    float4 hv = *(const float4*)(b1 + 4 * lid);
    #pragma unroll 4
    for (int i = 0; i < 64; ++i) {
        float fv = feat_s[i];
        float4 w = *(const float4*)(w1 + i * 256 + 4 * lid);
        hv.x += fv * w.x; hv.y += fv * w.y; hv.z += fv * w.z; hv.w += fv * w.w;
    }
    *(float4*)&h_s[4 * lid] = make_float4(fmaxf(hv.x, 0.f), fmaxf(hv.y, 0.f),
                                          fmaxf(hv.z, 0.f), fmaxf(hv.w, 0.f));
    __syncthreads();

    float o0 = 0.f, o1 = 0.f, o2 = 0.f, o3 = 0.f;
    #pragma unroll 4
    for (int j = 0; j < 256; j += 4) {
        o0 += h_s[j + 0] * w2[(j + 0) * 64 + lid];
        o1 += h_s[j + 1] * w2[(j + 1) * 64 + lid];
        o2 += h_s[j + 2] * w2[(j + 2) * 64 + lid];
        o3 += h_s[j + 3] * w2[(j + 3) * 64 + lid];
    }
    out[(long long)b * 64 + lid] = b2[lid] + (o0 + o1) + (o2 + o3);
}

extern "C" void kernel_launch(void* const* d_in, const int* in_sizes, int n_in,
                              void* d_out, int out_size, void* d_ws, size_t ws_size,
                              hipStream_t stream)
{
    const float* rp0      = (const float*)d_in[0];
    const float* rp1      = (const float*)d_in[1];
    const float* rp2      = (const float*)d_in[2];
    const float* rp3      = (const float*)d_in[3];
    const float* times    = (const float*)d_in[4];
    const float* now_time = (const float*)d_in[5];
    const float* w1       = (const float*)d_in[6];
    const float* b1       = (const float*)d_in[7];
    const float* w2       = (const float*)d_in[8];
    const float* b2       = (const float*)d_in[9];
    const int*   src_ids  = (const int*)d_in[10];
    const int*   dst_ids  = (const int*)d_in[11];
    const int*   q_src    = (const int*)d_in[12];
    const int*   q_dst    = (const int*)d_in[13];
    float* out = (float*)d_out;

    long long ND = in_sizes[0];      // N * D
    int N = (int)(ND / D);
    int E = in_sizes[4];
    int B = in_sizes[12];
    int NB = (N + CHUNK - 1) / CHUNK;

    float* new1 = (float*)d_ws;
    float* new2 = new1 + ND;
    float* new3 = new2 + ND;

    size_t base_bytes = (size_t)3 * ND * sizeof(float);
    size_t extra_bytes = (size_t)(2 * N + (N + 1) + 2 * E + NB) * sizeof(int)
                       + (size_t)(2 * E) * sizeof(float)
                       + (size_t)B * 64 * sizeof(float)
                       + (size_t)64 * 256 * sizeof(float);

    if (ws_size >= base_bytes + extra_bytes && NB <= 65536) {
        int* cnt       = (int*)(new3 + ND);           // N (becomes cursor)
        int* flag      = cnt + N;                     // N
        int* row_start = flag + N;                    // N+1
        int* adj_other = row_start + N + 1;           // 2E
        float* adj_tw  = (float*)(adj_other + 2 * E); // 2E
        int* bsum      = (int*)(adj_tw + 2 * E);      // NB
        float* feat    = (float*)(bsum + NB);         // B*64
        float* w1t     = feat + (size_t)B * 64;       // 64*256

        hipMemsetAsync(cnt, 0, (size_t)2 * N * sizeof(int), stream);  // cnt + flag
        int twoE = 2 * E;
        hist_kernel<<<(twoE + 255) / 256, 256, 0, stream>>>(src_ids, dst_ids, E, cnt);
        set_flags<<<(B + 255) / 256, 256, 0, stream>>>(q_src, q_dst, B, flag);
        transpose_w1<<<64, 256, 0, stream>>>(w1, w1t);
        scan_partial<<<NB, 256, 0, stream>>>(cnt, N, bsum);
        scan_blocksums<<<1, 256, 0, stream>>>(bsum, NB, row_start, N);
        scan_apply<<<NB, 256, 0, stream>>>(cnt, bsum, row_start, N);
        fill_kernel<<<(twoE + 255) / 256, 256, 0, stream>>>(src_ids, dst_ids, times, E,
                                                            cnt, adj_other, adj_tw);
        dim3 grid(N, 3);
        apply_updates<<<grid, 64, 0, stream>>>(rp0, rp1, rp2, rp3, times, now_time, E,
                                               row_start, adj_other, adj_tw, flag,
                                               new1, new2, new3);
        gather_gram<<<B, 64, 0, stream>>>(rp0, new1, new2, new3, q_src, q_dst, feat, B);
        mlp_kernel<<<(B + 63) / 64, 64, 0, stream>>>(feat, w1t, b1, w2, b2, out, B);
    } else {
        long long n4 = ND / 4;
        init_tables<<<2048, 256, 0, stream>>>(rp1, rp2, rp3, times, now_time, E,
                                              new1, new2, new3, n4);
        scatter_edges<<<E, 256, 0, stream>>>(rp0, rp1, rp2, times, now_time,
                                             src_ids, dst_ids, E, new1, new2, new3);
        pair_feature_mlp<<<B, 64, 0, stream>>>(rp0, new1, new2, new3, q_src, q_dst,
                                               w1, b1, w2, b2, out, B);
    }
}